// Round 3
// baseline (1087.034 us; speedup 1.0000x reference)
//
#include <hip/hip_runtime.h>
#include <hip/hip_bf16.h>

#define E_EDGES   1000000
#define TILE_E    64
#define N_TILES   (E_EDGES / TILE_E)   // 15625
#define IN_DIM_K  128
#define HID_N     256
#define BN_EPS_F  1e-5f
#define MAIN_GRID 1024

typedef __attribute__((ext_vector_type(4))) float f32x4;
typedef __attribute__((ext_vector_type(8))) short bf16x8;

__device__ __forceinline__ unsigned short f2bf(float f) {
    __hip_bfloat16 h = __float2bfloat16(f);
    return *reinterpret_cast<unsigned short*>(&h);
}
__device__ __forceinline__ unsigned pack2(float lo, float hi) {
    return (unsigned)f2bf(lo) | ((unsigned)f2bf(hi) << 16);
}

union FragU { uint4 u; bf16x8 v; unsigned w[4]; };

__global__ void zero_stats_kernel(float* g) {
    g[threadIdx.x] = 0.0f;   // 512 threads
}

__global__ void finalize_stats_kernel(const float* __restrict__ gstat,
                                      const float* __restrict__ gamma,
                                      const float* __restrict__ beta,
                                      float* __restrict__ nAB) {
    int c = threadIdx.x;     // 256 threads
    float inv_e = 1.0f / (float)E_EDGES;
    float mean = gstat[c] * inv_e;
    float var  = fmaxf(gstat[256 + c] * inv_e - mean * mean, 0.0f);
    float a = gamma[c] * rsqrtf(var + BN_EPS_F);
    nAB[c] = a;
    nAB[256 + c] = beta[c] - mean * a;
}

// 512 threads = 8 waves, wave grid 2(m) x 4(n). Tile: 64 edges x 256 ch.
// Pipelined: gather(t+1) issues into regs while MFMA(t) runs; LDS dbuf;
// ONE barrier per tile. Pass 2 y-reduction is a delayed epilogue.
template <bool STATS>
__global__ __launch_bounds__(512, 4)
void hadamard_mlp_kernel(const float* __restrict__ nodes,
                         const int* __restrict__ eidx,
                         const float* __restrict__ W1,
                         const float* __restrict__ W2,
                         const float* __restrict__ b2p,
                         float* __restrict__ gstat,
                         const float* __restrict__ nAB,
                         float* __restrict__ y)
{
    __shared__ unsigned sh_d[2][TILE_E * 68];   // 64 rows x 136 bf16, dbuf
    __shared__ float s_red[2][256];             // 4 wn-waves x 64 edges, dbuf

    const int tid  = threadIdx.x;
    const int lane = tid & 63;
    const int w    = tid >> 6;
    const int wm   = w >> 2;
    const int wn   = w & 3;
    const int l15  = lane & 15;
    const int l4   = lane >> 4;

    // ---- B fragments from W1 (f32 [128][256] row-major) ----
    bf16x8 bfrag[4][4];
    #pragma unroll
    for (int nt = 0; nt < 4; ++nt) {
        const int c = wn * 64 + nt * 16 + l15;
        #pragma unroll
        for (int kk = 0; kk < 4; ++kk) {
            const int kb = kk * 32 + 8 * l4;
            FragU t;
            #pragma unroll
            for (int j = 0; j < 4; ++j) {
                float w0 = W1[(kb + 2 * j    ) * HID_N + c];
                float w1 = W1[(kb + 2 * j + 1) * HID_N + c];
                t.w[j] = pack2(w0, w1);
            }
            bfrag[nt][kk] = t.v;
        }
    }

    float a_n[4], b_n[4], w2_n[4];
    if (!STATS) {
        #pragma unroll
        for (int nt = 0; nt < 4; ++nt) {
            const int c = wn * 64 + nt * 16 + l15;
            a_n[nt]  = nAB[c];
            b_n[nt]  = nAB[256 + c];
            w2_n[nt] = W2[c];
        }
    }
    const float b2v = b2p[0];

    float s1[4] = {0.f, 0.f, 0.f, 0.f};
    float s2[4] = {0.f, 0.f, 0.f, 0.f};

    const int ge   = tid >> 3;   // local edge 0..63
    const int part = tid & 7;    // 16-float chunk of the 128-dim row

    // ---- software pipeline state ----
    float4 g[8];                 // gathered src/dst chunks for next-staged tile
    int si, di;                  // edge indices one tile further ahead

    const int t0 = blockIdx.x;
    {
        const int e0 = t0 * TILE_E + ge;
        si = eidx[e0];
        di = eidx[E_EDGES + e0];
    }
    {   // issue gather for tile t0
        const float4* ps = reinterpret_cast<const float4*>(nodes + (size_t)si * IN_DIM_K) + part * 4;
        const float4* pd = reinterpret_cast<const float4*>(nodes + (size_t)di * IN_DIM_K) + part * 4;
        #pragma unroll
        for (int j = 0; j < 4; ++j) { g[j] = ps[j]; g[4 + j] = pd[j]; }
    }
    {   // prefetch indices for t0 + grid
        const int t1 = t0 + gridDim.x;
        if (t1 < N_TILES) {
            const int e1 = t1 * TILE_E + ge;
            si = eidx[e1];
            di = eidx[E_EDGES + e1];
        }
    }

    int cur = 0;
    int ptile = -1;   // tile whose y-partials sit in s_red[cur^1]

    for (int tile = t0; tile < N_TILES; tile += gridDim.x) {
        // ---- pack + write staged gather into sh_d[cur] ----
        {
            unsigned buf[8];
            #pragma unroll
            for (int j = 0; j < 4; ++j) {
                buf[2 * j]     = pack2(g[j].x * g[4 + j].x, g[j].y * g[4 + j].y);
                buf[2 * j + 1] = pack2(g[j].z * g[4 + j].z, g[j].w * g[4 + j].w);
            }
            unsigned* dst = sh_d[cur] + ge * 68 + part * 8;
            *reinterpret_cast<uint4*>(dst)     = *reinterpret_cast<const uint4*>(buf);
            *reinterpret_cast<uint4*>(dst + 4) = *reinterpret_cast<const uint4*>(buf + 4);
        }
        // ---- issue gather for next tile (in flight during MFMA) ----
        const int ntile = tile + gridDim.x;
        if (ntile < N_TILES) {
            const float4* ps = reinterpret_cast<const float4*>(nodes + (size_t)si * IN_DIM_K) + part * 4;
            const float4* pd = reinterpret_cast<const float4*>(nodes + (size_t)di * IN_DIM_K) + part * 4;
            #pragma unroll
            for (int j = 0; j < 4; ++j) { g[j] = ps[j]; g[4 + j] = pd[j]; }
        }
        // ---- prefetch indices two tiles ahead ----
        {
            const int n2 = tile + 2 * gridDim.x;
            if (n2 < N_TILES) {
                const int e2 = n2 * TILE_E + ge;
                si = eidx[e2];
                di = eidx[E_EDGES + e2];
            }
        }

        __syncthreads();   // sh_d[cur] visible; s_red[cur^1] complete

        // ---- delayed y epilogue for previous tile ----
        if (!STATS && ptile >= 0 && tid < TILE_E) {
            const float* r = s_red[cur ^ 1];
            y[ptile * TILE_E + tid] = r[tid] + r[64 + tid] + r[128 + tid]
                                    + r[192 + tid] + b2v;
        }

        // ---- MFMA: hraw tile (this wave: 32 edges x 64 channels) ----
        f32x4 acc[2][4] = {};
        #pragma unroll
        for (int kk = 0; kk < 4; ++kk) {
            bf16x8 af[2];
            #pragma unroll
            for (int mt = 0; mt < 2; ++mt) {
                const int row = wm * 32 + mt * 16 + l15;
                FragU t;
                t.u = *reinterpret_cast<const uint4*>(sh_d[cur] + row * 68 + kk * 16 + 4 * l4);
                af[mt] = t.v;
            }
            #pragma unroll
            for (int mt = 0; mt < 2; ++mt)
                #pragma unroll
                for (int nt = 0; nt < 4; ++nt)
                    acc[mt][nt] = __builtin_amdgcn_mfma_f32_16x16x32_bf16(
                        af[mt], bfrag[nt][kk], acc[mt][nt], 0, 0, 0);
        }

        if (STATS) {
            #pragma unroll
            for (int nt = 0; nt < 4; ++nt) {
                float t1s = 0.f, t2s = 0.f;
                #pragma unroll
                for (int mt = 0; mt < 2; ++mt)
                    #pragma unroll
                    for (int r = 0; r < 4; ++r) {
                        float v = acc[mt][nt][r];
                        t1s += v;
                        t2s += v * v;
                    }
                s1[nt] += t1s;
                s2[nt] += t2s;
            }
        } else {
            // y partials: z = relu(h*A+B); pw = sum_n z*W2
            float pw[2][4];
            #pragma unroll
            for (int mt = 0; mt < 2; ++mt)
                #pragma unroll
                for (int r = 0; r < 4; ++r) {
                    float acc_y = 0.f;
                    #pragma unroll
                    for (int nt = 0; nt < 4; ++nt) {
                        float z = acc[mt][nt][r] * a_n[nt] + b_n[nt];
                        z = fmaxf(z, 0.f);
                        acc_y += z * w2_n[nt];
                    }
                    pw[mt][r] = acc_y;
                }
            #pragma unroll
            for (int off = 1; off < 16; off <<= 1)
                #pragma unroll
                for (int mt = 0; mt < 2; ++mt)
                    #pragma unroll
                    for (int r = 0; r < 4; ++r)
                        pw[mt][r] += __shfl_xor(pw[mt][r], off, 64);
            if (l15 == 0) {
                #pragma unroll
                for (int mt = 0; mt < 2; ++mt)
                    #pragma unroll
                    for (int r = 0; r < 4; ++r) {
                        const int el = wm * 32 + mt * 16 + l4 * 4 + r;
                        s_red[cur][wn * 64 + el] = pw[mt][r];
                    }
            }
            ptile = tile;
        }
        cur ^= 1;
    }

    if (STATS) {
        #pragma unroll
        for (int nt = 0; nt < 4; ++nt) {
            s1[nt] += __shfl_xor(s1[nt], 16, 64);
            s1[nt] += __shfl_xor(s1[nt], 32, 64);
            s2[nt] += __shfl_xor(s2[nt], 16, 64);
            s2[nt] += __shfl_xor(s2[nt], 32, 64);
        }
        if (l4 == 0) {
            #pragma unroll
            for (int nt = 0; nt < 4; ++nt) {
                const int c = wn * 64 + nt * 16 + l15;
                atomicAdd(&gstat[c],       s1[nt]);
                atomicAdd(&gstat[256 + c], s2[nt]);
            }
        }
    } else {
        // drain the last pending y tile
        __syncthreads();
        if (ptile >= 0 && tid < TILE_E) {
            const float* r = s_red[cur ^ 1];
            y[ptile * TILE_E + tid] = r[tid] + r[64 + tid] + r[128 + tid]
                                    + r[192 + tid] + b2v;
        }
    }
}

extern "C" void kernel_launch(void* const* d_in, const int* in_sizes, int n_in,
                              void* d_out, int out_size, void* d_ws, size_t ws_size,
                              hipStream_t stream) {
    const float* nodes = (const float*)d_in[0];
    const int*   eidx  = (const int*)d_in[1];
    const float* W1    = (const float*)d_in[2];
    // d_in[3] = b1 : analytically cancelled by batch-norm, unused
    const float* gamma = (const float*)d_in[4];
    const float* beta  = (const float*)d_in[5];
    const float* W2    = (const float*)d_in[6];
    const float* b2    = (const float*)d_in[7];

    float* ws    = (float*)d_ws;
    float* gstat = ws;          // 512 f32: sum_h[256], sumsq_h[256]
    float* nAB   = ws + 512;    // 512 f32: A[256], B[256]
    float* y     = (float*)d_out;

    zero_stats_kernel<<<1, 512, 0, stream>>>(gstat);
    hadamard_mlp_kernel<true><<<MAIN_GRID, 512, 0, stream>>>(
        nodes, eidx, W1, W2, b2, gstat, nAB, y);
    finalize_stats_kernel<<<1, 256, 0, stream>>>(gstat, gamma, beta, nAB);
    hadamard_mlp_kernel<false><<<MAIN_GRID, 512, 0, stream>>>(
        nodes, eidx, W1, W2, b2, gstat, nAB, y);
}

// Round 4
// 322.184 us; speedup vs baseline: 3.3739x; 3.3739x over previous
//
#include <hip/hip_runtime.h>
#include <hip/hip_bf16.h>

#define E_EDGES   1000000
#define TILE_E    64
#define N_TILES   (E_EDGES / TILE_E)   // 15625
#define IN_DIM_K  128
#define HID_N     256
#define BN_EPS_F  1e-5f
#define MAIN_GRID 256

typedef __attribute__((ext_vector_type(4))) float f32x4;
typedef __attribute__((ext_vector_type(8))) short bf16x8;

__device__ __forceinline__ unsigned short f2bf(float f) {
    __hip_bfloat16 h = __float2bfloat16(f);
    return *reinterpret_cast<unsigned short*>(&h);
}
__device__ __forceinline__ unsigned pack2(float lo, float hi) {
    return (unsigned)f2bf(lo) | ((unsigned)f2bf(hi) << 16);
}

union FragU { uint4 u; bf16x8 v; unsigned w[4]; };

__global__ void zero_stats_kernel(float* g) {
    g[threadIdx.x] = 0.0f;   // 512 threads
}

__global__ void finalize_stats_kernel(const float* __restrict__ gstat,
                                      const float* __restrict__ gamma,
                                      const float* __restrict__ beta,
                                      float* __restrict__ nAB) {
    int c = threadIdx.x;     // 256 threads
    float inv_e = 1.0f / (float)E_EDGES;
    float mean = gstat[c] * inv_e;
    float var  = fmaxf(gstat[256 + c] * inv_e - mean * mean, 0.0f);
    float a = gamma[c] * rsqrtf(var + BN_EPS_F);
    nAB[c] = a;
    nAB[256 + c] = beta[c] - mean * a;
}

// 512 threads = 8 waves, wave grid 2(m) x 4(n). Tile: 64 edges x 256 ch.
// Pipelined: gather(t+1) issues into regs while MFMA(t) runs; LDS dbuf;
// ONE barrier per tile. Pass 2 y-reduction is a delayed epilogue.
// launch_bounds(512,2): cap 256 regs/wave — bfrag+acc live in AGPRs,
// g[] in-flight state in VGPRs, NO spill (round-3 lesson: (512,4) cap=128
// forced ~70 regs/thread of scratch spill -> 910 MB writes).
template <bool STATS>
__global__ __launch_bounds__(512, 2)
void hadamard_mlp_kernel(const float* __restrict__ nodes,
                         const int* __restrict__ eidx,
                         const float* __restrict__ W1,
                         const float* __restrict__ W2,
                         const float* __restrict__ b2p,
                         float* __restrict__ gstat,
                         const float* __restrict__ nAB,
                         float* __restrict__ y)
{
    __shared__ unsigned sh_d[2][TILE_E * 68];   // 64 rows x 136 bf16, dbuf
    __shared__ float s_red[2][256];             // 4 wn-waves x 64 edges, dbuf

    const int tid  = threadIdx.x;
    const int lane = tid & 63;
    const int w    = tid >> 6;
    const int wm   = w >> 2;
    const int wn   = w & 3;
    const int l15  = lane & 15;
    const int l4   = lane >> 4;

    // ---- B fragments from W1 (f32 [128][256] row-major) ----
    bf16x8 bfrag[4][4];
    #pragma unroll
    for (int nt = 0; nt < 4; ++nt) {
        const int c = wn * 64 + nt * 16 + l15;
        #pragma unroll
        for (int kk = 0; kk < 4; ++kk) {
            const int kb = kk * 32 + 8 * l4;
            FragU t;
            #pragma unroll
            for (int j = 0; j < 4; ++j) {
                float w0 = W1[(kb + 2 * j    ) * HID_N + c];
                float w1 = W1[(kb + 2 * j + 1) * HID_N + c];
                t.w[j] = pack2(w0, w1);
            }
            bfrag[nt][kk] = t.v;
        }
    }

    float a_n[4], b_n[4], w2_n[4];
    if (!STATS) {
        #pragma unroll
        for (int nt = 0; nt < 4; ++nt) {
            const int c = wn * 64 + nt * 16 + l15;
            a_n[nt]  = nAB[c];
            b_n[nt]  = nAB[256 + c];
            w2_n[nt] = W2[c];
        }
    }
    const float b2v = b2p[0];

    float s1[4] = {0.f, 0.f, 0.f, 0.f};
    float s2[4] = {0.f, 0.f, 0.f, 0.f};

    const int ge   = tid >> 3;   // local edge 0..63
    const int part = tid & 7;    // 16-float chunk of the 128-dim row

    // ---- software pipeline state ----
    float4 g[8];                 // gathered src/dst chunks for next-staged tile
    int si, di;                  // edge indices one tile further ahead

    const int t0 = blockIdx.x;
    {
        const int e0 = t0 * TILE_E + ge;
        si = eidx[e0];
        di = eidx[E_EDGES + e0];
    }
    {   // issue gather for tile t0
        const float4* ps = reinterpret_cast<const float4*>(nodes + (size_t)si * IN_DIM_K) + part * 4;
        const float4* pd = reinterpret_cast<const float4*>(nodes + (size_t)di * IN_DIM_K) + part * 4;
        #pragma unroll
        for (int j = 0; j < 4; ++j) { g[j] = ps[j]; g[4 + j] = pd[j]; }
    }
    {   // prefetch indices for t0 + grid
        const int t1 = t0 + gridDim.x;
        if (t1 < N_TILES) {
            const int e1 = t1 * TILE_E + ge;
            si = eidx[e1];
            di = eidx[E_EDGES + e1];
        }
    }

    int cur = 0;
    int ptile = -1;   // tile whose y-partials sit in s_red[cur^1]

    for (int tile = t0; tile < N_TILES; tile += gridDim.x) {
        // ---- pack + write staged gather into sh_d[cur] ----
        {
            unsigned buf[8];
            #pragma unroll
            for (int j = 0; j < 4; ++j) {
                buf[2 * j]     = pack2(g[j].x * g[4 + j].x, g[j].y * g[4 + j].y);
                buf[2 * j + 1] = pack2(g[j].z * g[4 + j].z, g[j].w * g[4 + j].w);
            }
            unsigned* dst = sh_d[cur] + ge * 68 + part * 8;
            *reinterpret_cast<uint4*>(dst)     = *reinterpret_cast<const uint4*>(buf);
            *reinterpret_cast<uint4*>(dst + 4) = *reinterpret_cast<const uint4*>(buf + 4);
        }
        // ---- issue gather for next tile (in flight during MFMA) ----
        const int ntile = tile + gridDim.x;
        if (ntile < N_TILES) {
            const float4* ps = reinterpret_cast<const float4*>(nodes + (size_t)si * IN_DIM_K) + part * 4;
            const float4* pd = reinterpret_cast<const float4*>(nodes + (size_t)di * IN_DIM_K) + part * 4;
            #pragma unroll
            for (int j = 0; j < 4; ++j) { g[j] = ps[j]; g[4 + j] = pd[j]; }
        }
        // ---- prefetch indices two tiles ahead ----
        {
            const int n2 = tile + 2 * gridDim.x;
            if (n2 < N_TILES) {
                const int e2 = n2 * TILE_E + ge;
                si = eidx[e2];
                di = eidx[E_EDGES + e2];
            }
        }

        __syncthreads();   // sh_d[cur] visible; s_red[cur^1] complete

        // ---- delayed y epilogue for previous tile ----
        if (!STATS && ptile >= 0 && tid < TILE_E) {
            const float* r = s_red[cur ^ 1];
            y[ptile * TILE_E + tid] = r[tid] + r[64 + tid] + r[128 + tid]
                                    + r[192 + tid] + b2v;
        }

        // ---- MFMA: hraw tile (this wave: 32 edges x 64 channels) ----
        f32x4 acc[2][4] = {};
        #pragma unroll
        for (int kk = 0; kk < 4; ++kk) {
            bf16x8 af[2];
            #pragma unroll
            for (int mt = 0; mt < 2; ++mt) {
                const int row = wm * 32 + mt * 16 + l15;
                FragU t;
                t.u = *reinterpret_cast<const uint4*>(sh_d[cur] + row * 68 + kk * 16 + 4 * l4);
                af[mt] = t.v;
            }
            #pragma unroll
            for (int mt = 0; mt < 2; ++mt)
                #pragma unroll
                for (int nt = 0; nt < 4; ++nt)
                    acc[mt][nt] = __builtin_amdgcn_mfma_f32_16x16x32_bf16(
                        af[mt], bfrag[nt][kk], acc[mt][nt], 0, 0, 0);
        }

        if (STATS) {
            #pragma unroll
            for (int nt = 0; nt < 4; ++nt) {
                float t1s = 0.f, t2s = 0.f;
                #pragma unroll
                for (int mt = 0; mt < 2; ++mt)
                    #pragma unroll
                    for (int r = 0; r < 4; ++r) {
                        float v = acc[mt][nt][r];
                        t1s += v;
                        t2s += v * v;
                    }
                s1[nt] += t1s;
                s2[nt] += t2s;
            }
        } else {
            // y partials: z = relu(h*A+B); pw = sum_n z*W2
            float pw[2][4];
            #pragma unroll
            for (int mt = 0; mt < 2; ++mt)
                #pragma unroll
                for (int r = 0; r < 4; ++r) {
                    float acc_y = 0.f;
                    #pragma unroll
                    for (int nt = 0; nt < 4; ++nt) {
                        float z = acc[mt][nt][r] * a_n[nt] + b_n[nt];
                        z = fmaxf(z, 0.f);
                        acc_y += z * w2_n[nt];
                    }
                    pw[mt][r] = acc_y;
                }
            #pragma unroll
            for (int off = 1; off < 16; off <<= 1)
                #pragma unroll
                for (int mt = 0; mt < 2; ++mt)
                    #pragma unroll
                    for (int r = 0; r < 4; ++r)
                        pw[mt][r] += __shfl_xor(pw[mt][r], off, 64);
            if (l15 == 0) {
                #pragma unroll
                for (int mt = 0; mt < 2; ++mt)
                    #pragma unroll
                    for (int r = 0; r < 4; ++r) {
                        const int el = wm * 32 + mt * 16 + l4 * 4 + r;
                        s_red[cur][wn * 64 + el] = pw[mt][r];
                    }
            }
            ptile = tile;
        }
        cur ^= 1;
    }

    if (STATS) {
        #pragma unroll
        for (int nt = 0; nt < 4; ++nt) {
            s1[nt] += __shfl_xor(s1[nt], 16, 64);
            s1[nt] += __shfl_xor(s1[nt], 32, 64);
            s2[nt] += __shfl_xor(s2[nt], 16, 64);
            s2[nt] += __shfl_xor(s2[nt], 32, 64);
        }
        if (l4 == 0) {
            #pragma unroll
            for (int nt = 0; nt < 4; ++nt) {
                const int c = wn * 64 + nt * 16 + l15;
                atomicAdd(&gstat[c],       s1[nt]);
                atomicAdd(&gstat[256 + c], s2[nt]);
            }
        }
    } else {
        // drain the last pending y tile
        __syncthreads();
        if (ptile >= 0 && tid < TILE_E) {
            const float* r = s_red[cur ^ 1];
            y[ptile * TILE_E + tid] = r[tid] + r[64 + tid] + r[128 + tid]
                                    + r[192 + tid] + b2v;
        }
    }
}

extern "C" void kernel_launch(void* const* d_in, const int* in_sizes, int n_in,
                              void* d_out, int out_size, void* d_ws, size_t ws_size,
                              hipStream_t stream) {
    const float* nodes = (const float*)d_in[0];
    const int*   eidx  = (const int*)d_in[1];
    const float* W1    = (const float*)d_in[2];
    // d_in[3] = b1 : analytically cancelled by batch-norm, unused
    const float* gamma = (const float*)d_in[4];
    const float* beta  = (const float*)d_in[5];
    const float* W2    = (const float*)d_in[6];
    const float* b2    = (const float*)d_in[7];

    float* ws    = (float*)d_ws;
    float* gstat = ws;          // 512 f32: sum_h[256], sumsq_h[256]
    float* nAB   = ws + 512;    // 512 f32: A[256], B[256]
    float* y     = (float*)d_out;

    zero_stats_kernel<<<1, 512, 0, stream>>>(gstat);
    hadamard_mlp_kernel<true><<<MAIN_GRID, 512, 0, stream>>>(
        nodes, eidx, W1, W2, b2, gstat, nAB, y);
    finalize_stats_kernel<<<1, 256, 0, stream>>>(gstat, gamma, beta, nAB);
    hadamard_mlp_kernel<false><<<MAIN_GRID, 512, 0, stream>>>(
        nodes, eidx, W1, W2, b2, gstat, nAB, y);
}

// Round 5
// 313.136 us; speedup vs baseline: 3.4714x; 1.0289x over previous
//
#include <hip/hip_runtime.h>
#include <hip/hip_bf16.h>

#define E_EDGES   1000000
#define TILE_E    64
#define N_TILES   (E_EDGES / TILE_E)   // 15625
#define IN_DIM_K  128
#define HID_N     256
#define BN_EPS_F  1e-5f
#define MAIN_GRID 256

typedef __attribute__((ext_vector_type(4))) float f32x4;
typedef __attribute__((ext_vector_type(8))) short bf16x8;

__device__ __forceinline__ unsigned short f2bf(float f) {
    __hip_bfloat16 h = __float2bfloat16(f);
    return *reinterpret_cast<unsigned short*>(&h);
}
__device__ __forceinline__ unsigned pack2(float lo, float hi) {
    return (unsigned)f2bf(lo) | ((unsigned)f2bf(hi) << 16);
}

union FragU { uint4 u; bf16x8 v; unsigned w[4]; };

__global__ void zero_stats_kernel(float* g) {
    g[threadIdx.x] = 0.0f;   // 512 threads
}

__global__ void finalize_stats_kernel(const float* __restrict__ gstat,
                                      const float* __restrict__ gamma,
                                      const float* __restrict__ beta,
                                      float* __restrict__ nAB) {
    int c = threadIdx.x;     // 256 threads
    float inv_e = 1.0f / (float)E_EDGES;
    float mean = gstat[c] * inv_e;
    float var  = fmaxf(gstat[256 + c] * inv_e - mean * mean, 0.0f);
    float a = gamma[c] * rsqrtf(var + BN_EPS_F);
    nAB[c] = a;
    nAB[256 + c] = beta[c] - mean * a;
}

// 512 threads = 8 waves, wave grid 2(m) x 4(n). Tile: 64 edges x 256 ch.
// DEPTH-2 gather pipeline: loads for tile t+2 issue in body(t) (named reg
// sets gA/gB, loop unrolled x2 -> static indexing, no scratch). Edge
// indices prefetched at distance 4. LDS dbuf, ONE barrier per tile.
// launch_bounds(512,2): 256-reg cap; (512,4) spills ~70 regs (round 3).
template <bool STATS>
__global__ __launch_bounds__(512, 2)
void hadamard_mlp_kernel(const float* __restrict__ nodes,
                         const int* __restrict__ eidx,
                         const float* __restrict__ W1,
                         const float* __restrict__ W2,
                         const float* __restrict__ b2p,
                         float* __restrict__ gstat,
                         const float* __restrict__ nAB,
                         float* __restrict__ y)
{
    __shared__ unsigned sh_d[2][TILE_E * 68];   // 64 rows x 136 bf16, dbuf
    __shared__ float s_red[2][256];             // 4 wn-waves x 64 edges, dbuf

    const int tid  = threadIdx.x;
    const int lane = tid & 63;
    const int w    = tid >> 6;
    const int wm   = w >> 2;
    const int wn   = w & 3;
    const int l15  = lane & 15;
    const int l4   = lane >> 4;

    // ---- B fragments from W1 (f32 [128][256] row-major) ----
    bf16x8 bfrag[4][4];
    #pragma unroll
    for (int nt = 0; nt < 4; ++nt) {
        const int c = wn * 64 + nt * 16 + l15;
        #pragma unroll
        for (int kk = 0; kk < 4; ++kk) {
            const int kb = kk * 32 + 8 * l4;
            FragU t;
            #pragma unroll
            for (int j = 0; j < 4; ++j) {
                float w0 = W1[(kb + 2 * j    ) * HID_N + c];
                float w1 = W1[(kb + 2 * j + 1) * HID_N + c];
                t.w[j] = pack2(w0, w1);
            }
            bfrag[nt][kk] = t.v;
        }
    }

    float a_n[4], b_n[4], w2_n[4];
    if (!STATS) {
        #pragma unroll
        for (int nt = 0; nt < 4; ++nt) {
            const int c = wn * 64 + nt * 16 + l15;
            a_n[nt]  = nAB[c];
            b_n[nt]  = nAB[256 + c];
            w2_n[nt] = W2[c];
        }
    }
    const float b2v = b2p[0];

    float s1[4] = {0.f, 0.f, 0.f, 0.f};
    float s2[4] = {0.f, 0.f, 0.f, 0.f};

    const int ge   = tid >> 3;   // local edge 0..63
    const int part = tid & 7;    // 16-float chunk of the 128-dim row

    // ---- software pipeline state: 2 gather sets + 2 idx sets ----
    float4 gA[8], gB[8];
    int siA, diA, siB, diB;

    const int t0 = blockIdx.x;
    {   // gather tile t0 into gA
        const int e0 = t0 * TILE_E + ge;
        const int s = eidx[e0];
        const int d = eidx[E_EDGES + e0];
        const float4* ps = reinterpret_cast<const float4*>(nodes + (size_t)s * IN_DIM_K) + part * 4;
        const float4* pd = reinterpret_cast<const float4*>(nodes + (size_t)d * IN_DIM_K) + part * 4;
        #pragma unroll
        for (int j = 0; j < 4; ++j) { gA[j] = ps[j]; gA[4 + j] = pd[j]; }
    }
    if (t0 + MAIN_GRID < N_TILES) {   // gather tile t0+G into gB
        const int e1 = (t0 + MAIN_GRID) * TILE_E + ge;
        const int s = eidx[e1];
        const int d = eidx[E_EDGES + e1];
        const float4* ps = reinterpret_cast<const float4*>(nodes + (size_t)s * IN_DIM_K) + part * 4;
        const float4* pd = reinterpret_cast<const float4*>(nodes + (size_t)d * IN_DIM_K) + part * 4;
        #pragma unroll
        for (int j = 0; j < 4; ++j) { gB[j] = ps[j]; gB[4 + j] = pd[j]; }
    }
    siA = diA = siB = diB = 0;
    if (t0 + 2 * MAIN_GRID < N_TILES) {
        const int e = (t0 + 2 * MAIN_GRID) * TILE_E + ge;
        siA = eidx[e];  diA = eidx[E_EDGES + e];
    }
    if (t0 + 3 * MAIN_GRID < N_TILES) {
        const int e = (t0 + 3 * MAIN_GRID) * TILE_E + ge;
        siB = eidx[e];  diB = eidx[E_EDGES + e];
    }

    int cur = 0;
    int ptile = -1;   // tile whose y-partials sit in s_red[cur^1]

#define PIPE_BODY(TILE, GV, SIV, DIV)                                          \
    {                                                                          \
        const int tile_ = (TILE);                                              \
        {   /* pack + write staged gather into sh_d[cur] */                    \
            unsigned buf[8];                                                   \
            _Pragma("unroll")                                                  \
            for (int j = 0; j < 4; ++j) {                                      \
                buf[2*j]   = pack2(GV[j].x * GV[4+j].x, GV[j].y * GV[4+j].y);  \
                buf[2*j+1] = pack2(GV[j].z * GV[4+j].z, GV[j].w * GV[4+j].w);  \
            }                                                                  \
            unsigned* dst = sh_d[cur] + ge * 68 + part * 8;                    \
            *reinterpret_cast<uint4*>(dst)     = *reinterpret_cast<const uint4*>(buf);     \
            *reinterpret_cast<uint4*>(dst + 4) = *reinterpret_cast<const uint4*>(buf + 4); \
        }                                                                      \
        /* issue gather for tile_+2G into GV (consumed 2 bodies later) */      \
        if (tile_ + 2 * MAIN_GRID < N_TILES) {                                 \
            const float4* ps = reinterpret_cast<const float4*>(nodes + (size_t)SIV * IN_DIM_K) + part * 4; \
            const float4* pd = reinterpret_cast<const float4*>(nodes + (size_t)DIV * IN_DIM_K) + part * 4; \
            _Pragma("unroll")                                                  \
            for (int j = 0; j < 4; ++j) { GV[j] = ps[j]; GV[4+j] = pd[j]; }    \
        }                                                                      \
        /* refill idx for tile_+4G (used 2 bodies later) */                    \
        if (tile_ + 4 * MAIN_GRID < N_TILES) {                                 \
            const int e_ = (tile_ + 4 * MAIN_GRID) * TILE_E + ge;              \
            SIV = eidx[e_];  DIV = eidx[E_EDGES + e_];                         \
        }                                                                      \
        __syncthreads();                                                       \
        /* delayed y epilogue for previous tile */                             \
        if (!STATS && ptile >= 0 && tid < TILE_E) {                            \
            const float* r = s_red[cur ^ 1];                                   \
            y[ptile * TILE_E + tid] = r[tid] + r[64 + tid] + r[128 + tid]      \
                                    + r[192 + tid] + b2v;                      \
        }                                                                      \
        /* MFMA: this wave: 32 edges x 64 channels */                          \
        f32x4 acc[2][4] = {};                                                  \
        _Pragma("unroll")                                                      \
        for (int kk = 0; kk < 4; ++kk) {                                       \
            bf16x8 af[2];                                                      \
            _Pragma("unroll")                                                  \
            for (int mt = 0; mt < 2; ++mt) {                                   \
                const int row = wm * 32 + mt * 16 + l15;                       \
                FragU t;                                                       \
                t.u = *reinterpret_cast<const uint4*>(sh_d[cur] + row * 68 + kk * 16 + 4 * l4); \
                af[mt] = t.v;                                                  \
            }                                                                  \
            _Pragma("unroll")                                                  \
            for (int mt = 0; mt < 2; ++mt)                                     \
                _Pragma("unroll")                                              \
                for (int nt = 0; nt < 4; ++nt)                                 \
                    acc[mt][nt] = __builtin_amdgcn_mfma_f32_16x16x32_bf16(     \
                        af[mt], bfrag[nt][kk], acc[mt][nt], 0, 0, 0);          \
        }                                                                      \
        if (STATS) {                                                           \
            _Pragma("unroll")                                                  \
            for (int nt = 0; nt < 4; ++nt) {                                   \
                float t1s = 0.f, t2s = 0.f;                                    \
                _Pragma("unroll")                                              \
                for (int mt = 0; mt < 2; ++mt)                                 \
                    _Pragma("unroll")                                          \
                    for (int r = 0; r < 4; ++r) {                              \
                        float v = acc[mt][nt][r];                              \
                        t1s += v;                                              \
                        t2s += v * v;                                          \
                    }                                                          \
                s1[nt] += t1s;                                                 \
                s2[nt] += t2s;                                                 \
            }                                                                  \
        } else {                                                               \
            float pw[2][4];                                                    \
            _Pragma("unroll")                                                  \
            for (int mt = 0; mt < 2; ++mt)                                     \
                _Pragma("unroll")                                              \
                for (int r = 0; r < 4; ++r) {                                  \
                    float acc_y = 0.f;                                         \
                    _Pragma("unroll")                                          \
                    for (int nt = 0; nt < 4; ++nt) {                           \
                        float z = acc[mt][nt][r] * a_n[nt] + b_n[nt];          \
                        z = fmaxf(z, 0.f);                                     \
                        acc_y += z * w2_n[nt];                                 \
                    }                                                          \
                    pw[mt][r] = acc_y;                                         \
                }                                                              \
            _Pragma("unroll")                                                  \
            for (int off = 1; off < 16; off <<= 1)                             \
                _Pragma("unroll")                                              \
                for (int mt = 0; mt < 2; ++mt)                                 \
                    _Pragma("unroll")                                          \
                    for (int r = 0; r < 4; ++r)                                \
                        pw[mt][r] += __shfl_xor(pw[mt][r], off, 64);           \
            if (l15 == 0) {                                                    \
                _Pragma("unroll")                                              \
                for (int mt = 0; mt < 2; ++mt)                                 \
                    _Pragma("unroll")                                          \
                    for (int r = 0; r < 4; ++r) {                              \
                        const int el = wm * 32 + mt * 16 + l4 * 4 + r;         \
                        s_red[cur][wn * 64 + el] = pw[mt][r];                  \
                    }                                                          \
            }                                                                  \
            ptile = tile_;                                                     \
        }                                                                      \
        cur ^= 1;                                                              \
    }

    for (int tile = t0; tile < N_TILES; tile += 2 * MAIN_GRID) {
        PIPE_BODY(tile, gA, siA, diA);
        const int tb = tile + MAIN_GRID;
        if (tb < N_TILES) {
            PIPE_BODY(tb, gB, siB, diB);
        }
    }
#undef PIPE_BODY

    if (STATS) {
        #pragma unroll
        for (int nt = 0; nt < 4; ++nt) {
            s1[nt] += __shfl_xor(s1[nt], 16, 64);
            s1[nt] += __shfl_xor(s1[nt], 32, 64);
            s2[nt] += __shfl_xor(s2[nt], 16, 64);
            s2[nt] += __shfl_xor(s2[nt], 32, 64);
        }
        if (l4 == 0) {
            #pragma unroll
            for (int nt = 0; nt < 4; ++nt) {
                const int c = wn * 64 + nt * 16 + l15;
                atomicAdd(&gstat[c],       s1[nt]);
                atomicAdd(&gstat[256 + c], s2[nt]);
            }
        }
    } else {
        // drain the last pending y tile
        __syncthreads();
        if (ptile >= 0 && tid < TILE_E) {
            const float* r = s_red[cur ^ 1];
            y[ptile * TILE_E + tid] = r[tid] + r[64 + tid] + r[128 + tid]
                                    + r[192 + tid] + b2v;
        }
    }
}

extern "C" void kernel_launch(void* const* d_in, const int* in_sizes, int n_in,
                              void* d_out, int out_size, void* d_ws, size_t ws_size,
                              hipStream_t stream) {
    const float* nodes = (const float*)d_in[0];
    const int*   eidx  = (const int*)d_in[1];
    const float* W1    = (const float*)d_in[2];
    // d_in[3] = b1 : analytically cancelled by batch-norm, unused
    const float* gamma = (const float*)d_in[4];
    const float* beta  = (const float*)d_in[5];
    const float* W2    = (const float*)d_in[6];
    const float* b2    = (const float*)d_in[7];

    float* ws    = (float*)d_ws;
    float* gstat = ws;          // 512 f32: sum_h[256], sumsq_h[256]
    float* nAB   = ws + 512;    // 512 f32: A[256], B[256]
    float* y     = (float*)d_out;

    zero_stats_kernel<<<1, 512, 0, stream>>>(gstat);
    hadamard_mlp_kernel<true><<<MAIN_GRID, 512, 0, stream>>>(
        nodes, eidx, W1, W2, b2, gstat, nAB, y);
    finalize_stats_kernel<<<1, 256, 0, stream>>>(gstat, gamma, beta, nAB);
    hadamard_mlp_kernel<false><<<MAIN_GRID, 512, 0, stream>>>(
        nodes, eidx, W1, W2, b2, gstat, nAB, y);
}

// Round 6
// 302.547 us; speedup vs baseline: 3.5929x; 1.0350x over previous
//
#include <hip/hip_runtime.h>
#include <hip/hip_bf16.h>

#define E_EDGES   1000000
#define TILE_E    32
#define N_TILES   (E_EDGES / TILE_E)   // 31250
#define IN_DIM_K  128
#define HID_N     256
#define BN_EPS_F  1e-5f
#define MAIN_GRID 512

typedef __attribute__((ext_vector_type(4))) float f32x4;
typedef __attribute__((ext_vector_type(8))) short bf16x8;

__device__ __forceinline__ unsigned short f2bf(float f) {
    __hip_bfloat16 h = __float2bfloat16(f);
    return *reinterpret_cast<unsigned short*>(&h);
}
__device__ __forceinline__ unsigned pack2(float lo, float hi) {
    return (unsigned)f2bf(lo) | ((unsigned)f2bf(hi) << 16);
}

union FragU { uint4 u; bf16x8 v; unsigned w[4]; };

__global__ void zero_stats_kernel(float* g) {
    g[threadIdx.x] = 0.0f;   // 512 threads
}

__global__ void finalize_stats_kernel(const float* __restrict__ gstat,
                                      const float* __restrict__ gamma,
                                      const float* __restrict__ beta,
                                      float* __restrict__ nAB) {
    int c = threadIdx.x;     // 256 threads
    float inv_e = 1.0f / (float)E_EDGES;
    float mean = gstat[c] * inv_e;
    float var  = fmaxf(gstat[256 + c] * inv_e - mean * mean, 0.0f);
    float a = gamma[c] * rsqrtf(var + BN_EPS_F);
    nAB[c] = a;
    nAB[256 + c] = beta[c] - mean * a;
}

// 256 threads = 4 waves (1m x 4n). Tile: 32 edges x 256 ch. Grid 512 =
// 2 INDEPENDENT blocks per CU (8 waves/CU, reg-capped) -> decoupled
// barriers let one block's MFMA phase overlap the other's gather/pack
// phase (m114 mechanism). Depth-2 gather pipeline kept (named gA/gB).
// launch_bounds(256,2): 256-reg cap, no spill (round-3 lesson).
template <bool STATS>
__global__ __launch_bounds__(256, 2)
void hadamard_mlp_kernel(const float* __restrict__ nodes,
                         const int* __restrict__ eidx,
                         const float* __restrict__ W1,
                         const float* __restrict__ W2,
                         const float* __restrict__ b2p,
                         float* __restrict__ gstat,
                         const float* __restrict__ nAB,
                         float* __restrict__ y)
{
    __shared__ unsigned sh_d[2][TILE_E * 68];   // 32 rows x 136 bf16, dbuf
    __shared__ float s_red[2][128];             // 4 wn-waves x 32 edges, dbuf

    const int tid  = threadIdx.x;
    const int lane = tid & 63;
    const int wn   = tid >> 6;        // 0..3 (N split)
    const int l15  = lane & 15;
    const int l4   = lane >> 4;

    // ---- B fragments from W1 (f32 [128][256] row-major) ----
    bf16x8 bfrag[4][4];
    #pragma unroll
    for (int nt = 0; nt < 4; ++nt) {
        const int c = wn * 64 + nt * 16 + l15;
        #pragma unroll
        for (int kk = 0; kk < 4; ++kk) {
            const int kb = kk * 32 + 8 * l4;
            FragU t;
            #pragma unroll
            for (int j = 0; j < 4; ++j) {
                float w0 = W1[(kb + 2 * j    ) * HID_N + c];
                float w1 = W1[(kb + 2 * j + 1) * HID_N + c];
                t.w[j] = pack2(w0, w1);
            }
            bfrag[nt][kk] = t.v;
        }
    }

    float a_n[4], b_n[4], w2_n[4];
    if (!STATS) {
        #pragma unroll
        for (int nt = 0; nt < 4; ++nt) {
            const int c = wn * 64 + nt * 16 + l15;
            a_n[nt]  = nAB[c];
            b_n[nt]  = nAB[256 + c];
            w2_n[nt] = W2[c];
        }
    }
    const float b2v = b2p[0];

    float s1[4] = {0.f, 0.f, 0.f, 0.f};
    float s2[4] = {0.f, 0.f, 0.f, 0.f};

    const int ge   = tid >> 3;   // local edge 0..31
    const int part = tid & 7;    // 16-float chunk of the 128-dim row

    // ---- software pipeline state: 2 gather sets + 2 idx sets ----
    float4 gA[8], gB[8];
    int siA, diA, siB, diB;

    const int t0 = blockIdx.x;
    {   // gather tile t0 into gA
        const int e0 = t0 * TILE_E + ge;
        const int s = eidx[e0];
        const int d = eidx[E_EDGES + e0];
        const float4* ps = reinterpret_cast<const float4*>(nodes + (size_t)s * IN_DIM_K) + part * 4;
        const float4* pd = reinterpret_cast<const float4*>(nodes + (size_t)d * IN_DIM_K) + part * 4;
        #pragma unroll
        for (int j = 0; j < 4; ++j) { gA[j] = ps[j]; gA[4 + j] = pd[j]; }
    }
    if (t0 + MAIN_GRID < N_TILES) {   // gather tile t0+G into gB
        const int e1 = (t0 + MAIN_GRID) * TILE_E + ge;
        const int s = eidx[e1];
        const int d = eidx[E_EDGES + e1];
        const float4* ps = reinterpret_cast<const float4*>(nodes + (size_t)s * IN_DIM_K) + part * 4;
        const float4* pd = reinterpret_cast<const float4*>(nodes + (size_t)d * IN_DIM_K) + part * 4;
        #pragma unroll
        for (int j = 0; j < 4; ++j) { gB[j] = ps[j]; gB[4 + j] = pd[j]; }
    }
    siA = diA = siB = diB = 0;
    if (t0 + 2 * MAIN_GRID < N_TILES) {
        const int e = (t0 + 2 * MAIN_GRID) * TILE_E + ge;
        siA = eidx[e];  diA = eidx[E_EDGES + e];
    }
    if (t0 + 3 * MAIN_GRID < N_TILES) {
        const int e = (t0 + 3 * MAIN_GRID) * TILE_E + ge;
        siB = eidx[e];  diB = eidx[E_EDGES + e];
    }

    int cur = 0;
    int ptile = -1;   // tile whose y-partials sit in s_red[cur^1]

#define PIPE_BODY(TILE, GV, SIV, DIV)                                          \
    {                                                                          \
        const int tile_ = (TILE);                                              \
        {   /* pack + write staged gather into sh_d[cur] */                    \
            unsigned buf[8];                                                   \
            _Pragma("unroll")                                                  \
            for (int j = 0; j < 4; ++j) {                                      \
                buf[2*j]   = pack2(GV[j].x * GV[4+j].x, GV[j].y * GV[4+j].y);  \
                buf[2*j+1] = pack2(GV[j].z * GV[4+j].z, GV[j].w * GV[4+j].w);  \
            }                                                                  \
            unsigned* dst = sh_d[cur] + ge * 68 + part * 8;                    \
            *reinterpret_cast<uint4*>(dst)     = *reinterpret_cast<const uint4*>(buf);     \
            *reinterpret_cast<uint4*>(dst + 4) = *reinterpret_cast<const uint4*>(buf + 4); \
        }                                                                      \
        /* issue gather for tile_+2G into GV (consumed 2 bodies later) */      \
        if (tile_ + 2 * MAIN_GRID < N_TILES) {                                 \
            const float4* ps = reinterpret_cast<const float4*>(nodes + (size_t)SIV * IN_DIM_K) + part * 4; \
            const float4* pd = reinterpret_cast<const float4*>(nodes + (size_t)DIV * IN_DIM_K) + part * 4; \
            _Pragma("unroll")                                                  \
            for (int j = 0; j < 4; ++j) { GV[j] = ps[j]; GV[4+j] = pd[j]; }    \
        }                                                                      \
        /* refill idx for tile_+4G (used 2 bodies later) */                    \
        if (tile_ + 4 * MAIN_GRID < N_TILES) {                                 \
            const int e_ = (tile_ + 4 * MAIN_GRID) * TILE_E + ge;              \
            SIV = eidx[e_];  DIV = eidx[E_EDGES + e_];                         \
        }                                                                      \
        __syncthreads();                                                       \
        /* delayed y epilogue for previous tile */                             \
        if (!STATS && ptile >= 0 && tid < TILE_E) {                            \
            const float* r = s_red[cur ^ 1];                                   \
            y[ptile * TILE_E + tid] = r[tid] + r[32 + tid] + r[64 + tid]       \
                                    + r[96 + tid] + b2v;                       \
        }                                                                      \
        /* MFMA: this wave: 32 edges x 64 channels */                          \
        f32x4 acc[2][4] = {};                                                  \
        __builtin_amdgcn_s_setprio(1);                                         \
        _Pragma("unroll")                                                      \
        for (int kk = 0; kk < 4; ++kk) {                                       \
            bf16x8 af[2];                                                      \
            _Pragma("unroll")                                                  \
            for (int mt = 0; mt < 2; ++mt) {                                   \
                const int row = mt * 16 + l15;                                 \
                FragU t;                                                       \
                t.u = *reinterpret_cast<const uint4*>(sh_d[cur] + row * 68 + kk * 16 + 4 * l4); \
                af[mt] = t.v;                                                  \
            }                                                                  \
            _Pragma("unroll")                                                  \
            for (int mt = 0; mt < 2; ++mt)                                     \
                _Pragma("unroll")                                              \
                for (int nt = 0; nt < 4; ++nt)                                 \
                    acc[mt][nt] = __builtin_amdgcn_mfma_f32_16x16x32_bf16(     \
                        af[mt], bfrag[nt][kk], acc[mt][nt], 0, 0, 0);          \
        }                                                                      \
        __builtin_amdgcn_s_setprio(0);                                         \
        if (STATS) {                                                           \
            _Pragma("unroll")                                                  \
            for (int nt = 0; nt < 4; ++nt) {                                   \
                float t1s = 0.f, t2s = 0.f;                                    \
                _Pragma("unroll")                                              \
                for (int mt = 0; mt < 2; ++mt)                                 \
                    _Pragma("unroll")                                          \
                    for (int r = 0; r < 4; ++r) {                              \
                        float v = acc[mt][nt][r];                              \
                        t1s += v;                                              \
                        t2s += v * v;                                          \
                    }                                                          \
                s1[nt] += t1s;                                                 \
                s2[nt] += t2s;                                                 \
            }                                                                  \
        } else {                                                               \
            float pw[2][4];                                                    \
            _Pragma("unroll")                                                  \
            for (int mt = 0; mt < 2; ++mt)                                     \
                _Pragma("unroll")                                              \
                for (int r = 0; r < 4; ++r) {                                  \
                    float acc_y = 0.f;                                         \
                    _Pragma("unroll")                                          \
                    for (int nt = 0; nt < 4; ++nt) {                           \
                        float z = acc[mt][nt][r] * a_n[nt] + b_n[nt];          \
                        z = fmaxf(z, 0.f);                                     \
                        acc_y += z * w2_n[nt];                                 \
                    }                                                          \
                    pw[mt][r] = acc_y;                                         \
                }                                                              \
            _Pragma("unroll")                                                  \
            for (int off = 1; off < 16; off <<= 1)                             \
                _Pragma("unroll")                                              \
                for (int mt = 0; mt < 2; ++mt)                                 \
                    _Pragma("unroll")                                          \
                    for (int r = 0; r < 4; ++r)                                \
                        pw[mt][r] += __shfl_xor(pw[mt][r], off, 64);           \
            if (l15 == 0) {                                                    \
                _Pragma("unroll")                                              \
                for (int mt = 0; mt < 2; ++mt)                                 \
                    _Pragma("unroll")                                          \
                    for (int r = 0; r < 4; ++r) {                              \
                        const int el = mt * 16 + l4 * 4 + r;                   \
                        s_red[cur][wn * 32 + el] = pw[mt][r];                  \
                    }                                                          \
            }                                                                  \
            ptile = tile_;                                                     \
        }                                                                      \
        cur ^= 1;                                                              \
    }

    for (int tile = t0; tile < N_TILES; tile += 2 * MAIN_GRID) {
        PIPE_BODY(tile, gA, siA, diA);
        const int tb = tile + MAIN_GRID;
        if (tb < N_TILES) {
            PIPE_BODY(tb, gB, siB, diB);
        }
    }
#undef PIPE_BODY

    if (STATS) {
        #pragma unroll
        for (int nt = 0; nt < 4; ++nt) {
            s1[nt] += __shfl_xor(s1[nt], 16, 64);
            s1[nt] += __shfl_xor(s1[nt], 32, 64);
            s2[nt] += __shfl_xor(s2[nt], 16, 64);
            s2[nt] += __shfl_xor(s2[nt], 32, 64);
        }
        if (l4 == 0) {
            #pragma unroll
            for (int nt = 0; nt < 4; ++nt) {
                const int c = wn * 64 + nt * 16 + l15;
                atomicAdd(&gstat[c],       s1[nt]);
                atomicAdd(&gstat[256 + c], s2[nt]);
            }
        }
    } else {
        // drain the last pending y tile
        __syncthreads();
        if (ptile >= 0 && tid < TILE_E) {
            const float* r = s_red[cur ^ 1];
            y[ptile * TILE_E + tid] = r[tid] + r[32 + tid] + r[64 + tid]
                                    + r[96 + tid] + b2v;
        }
    }
}

extern "C" void kernel_launch(void* const* d_in, const int* in_sizes, int n_in,
                              void* d_out, int out_size, void* d_ws, size_t ws_size,
                              hipStream_t stream) {
    const float* nodes = (const float*)d_in[0];
    const int*   eidx  = (const int*)d_in[1];
    const float* W1    = (const float*)d_in[2];
    // d_in[3] = b1 : analytically cancelled by batch-norm, unused
    const float* gamma = (const float*)d_in[4];
    const float* beta  = (const float*)d_in[5];
    const float* W2    = (const float*)d_in[6];
    const float* b2    = (const float*)d_in[7];

    float* ws    = (float*)d_ws;
    float* gstat = ws;          // 512 f32: sum_h[256], sumsq_h[256]
    float* nAB   = ws + 512;    // 512 f32: A[256], B[256]
    float* y     = (float*)d_out;

    zero_stats_kernel<<<1, 512, 0, stream>>>(gstat);
    hadamard_mlp_kernel<true><<<MAIN_GRID, 256, 0, stream>>>(
        nodes, eidx, W1, W2, b2, gstat, nAB, y);
    finalize_stats_kernel<<<1, 256, 0, stream>>>(gstat, gamma, beta, nAB);
    hadamard_mlp_kernel<false><<<MAIN_GRID, 256, 0, stream>>>(
        nodes, eidx, W1, W2, b2, gstat, nAB, y);
}